// Round 15
// baseline (135.389 us; speedup 1.0000x reference)
//
#include <hip/hip_runtime.h>
#include <math.h>

// n=16384 Gaussian points in 3D. Exact 12-NN (incl self) per point:
//   out[i] = b + ( (W·p_i)·(1 + 11/sqrt(2)) + 0.5 * sum_{11NN} W·|p_i - p_j| ) / 12
//
// R15: parallel 3-axis counting sort in 4 wide stream-ordered dispatches
// (R14's grid=3 sort ran hist+scan+scatter of 16384 points on ONE CU per
// axis ≈ 65 µs of the 133 µs total):
//   memset(hist) -> hist (16384 thr, 3 global atomics/pt over 6144 lines)
//   -> scan (3 blocks x 1024, LDS prefix; writes end-cursors for the query
//   and start-cursors for the scatter) -> scatter (16384 thr x 3 axes,
//   global-atomic cursor grab, stores spread over all CUs).
// Query kernel unchanged from R13/R14 (twice-verified: 67 µs, VALUBusy ~50%):
//   one wave per query; pick axis with max |coord| (min slab mass -> ~uniform
//   extents); seed 768 around bin-estimated rank -> per-lane min d2 -> u =
//   12th of 64 lane minima (valid UB of tau) -> extent from prefix sums ->
//   fixed-trip collect into 4-deep paired (d2,w) buffer -> 12-round paired
//   knockout (exact take-12, first-lane tie-break) -> reduce, write.
//   Overflow (rare, wave-uniform) -> exact med3 fallback over same extent.

#define NBINS  2048
#define CMIN_  (-6.0f)
#define INVBW_ ((float)NBINS / 12.0f)
#define BLOCK  256
#define WPB    4
#define SEED   768
#define KK     12
#define CD     4
#define BIG    3.0e38f

__device__ __forceinline__ int bin_of(float x) {
  int b = (int)((x - CMIN_) * INVBW_);
  b = b < 0 ? 0 : b;
  b = b > NBINS - 1 ? NBINS - 1 : b;
  return b;
}

__device__ __forceinline__ float wave_min(float v) {
#pragma unroll
  for (int o = 1; o < 64; o <<= 1) v = fminf(v, __shfl_xor(v, o));
  return v;
}

// sorted ascending 4-deep paired insert (static indexing -> registers)
__device__ __forceinline__ void ins4(float (&qd)[CD], float (&qw)[CD],
                                     float d, float w) {
#pragma unroll
  for (int k = CD - 1; k >= 1; --k) {
    const bool up  = (qd[k - 1] > d);
    const bool mid = (qd[k] > d);
    const float nd = up ? qd[k - 1] : (mid ? d : qd[k]);
    const float nw = up ? qw[k - 1] : (mid ? w : qw[k]);
    qd[k] = nd; qw[k] = nw;
  }
  if (qd[0] > d) { qw[0] = w; qd[0] = d; }
}

// ---------------- K1: 3-axis histogram (wide) --------------------------------
__global__ __launch_bounds__(256)
void hist_kernel(const float* __restrict__ p, int* __restrict__ hist, int n) {
  const int i = blockIdx.x * 256 + threadIdx.x;
  if (i < n) {
    const float x = p[3 * i], y = p[3 * i + 1], z = p[3 * i + 2];
    atomicAdd(&hist[bin_of(x)], 1);
    atomicAdd(&hist[NBINS + bin_of(y)], 1);
    atomicAdd(&hist[2 * NBINS + bin_of(z)], 1);
  }
}

// ---------------- K2: per-axis scan (3 blocks x 1024) ------------------------
// cursorEnd[b] = end of bin b (query-side); scatCur[b] = start (scatter-side).
__global__ __launch_bounds__(1024)
void scan_kernel(const int* __restrict__ hist, int* __restrict__ cursorEnd,
                 int* __restrict__ scatCur) {
  __shared__ int ssum[1024];
  const int tid = threadIdx.x;
  const int dim = blockIdx.x;
  const int* __restrict__ h = hist + dim * NBINS;
  int* __restrict__ ce = cursorEnd + dim * NBINS;
  int* __restrict__ sc = scatCur + dim * NBINS;

  const int a = h[2 * tid], b = h[2 * tid + 1];
  ssum[tid] = a + b;
  __syncthreads();
  for (int off = 1; off < 1024; off <<= 1) {
    const int v = (tid >= off) ? ssum[tid - off] : 0;
    __syncthreads();
    ssum[tid] += v;
    __syncthreads();
  }
  const int excl = ssum[tid] - (a + b);
  sc[2 * tid]     = excl;
  sc[2 * tid + 1] = excl + a;
  ce[2 * tid]     = excl + a;
  ce[2 * tid + 1] = excl + a + b;
}

// ---------------- K3: 3-axis scatter (wide) ----------------------------------
__global__ __launch_bounds__(256)
void scatter_kernel(const float* __restrict__ p, int* __restrict__ scatCur,
                    float4* __restrict__ s_all, int n) {
  const int i = blockIdx.x * 256 + threadIdx.x;
  if (i < n) {
    const float x = p[3 * i], y = p[3 * i + 1], z = p[3 * i + 2];
    const float4 v = make_float4(x, y, z, __int_as_float(i));
    const int bx = bin_of(x), by = bin_of(y), bz = bin_of(z);
    const int px = atomicAdd(&scatCur[bx], 1);
    const int py = atomicAdd(&scatCur[NBINS + by], 1);
    const int pz = atomicAdd(&scatCur[2 * NBINS + bz], 1);
    s_all[px] = v;
    s_all[n + py] = v;
    s_all[2 * n + pz] = v;
  }
}

// ---------------- K4: query (one wave per query, best-axis extent) -----------
__global__ __launch_bounds__(BLOCK)
void query_kernel(const float4* __restrict__ sx, const float4* __restrict__ sy,
                  const float4* __restrict__ sz, const int* __restrict__ cx,
                  const int* __restrict__ cy, const int* __restrict__ cz,
                  const float* __restrict__ W, const float* __restrict__ bias,
                  float* __restrict__ out, int n) {
  const int lane = threadIdx.x & 63;
  const int wv   = threadIdx.x >> 6;
  const int t    = wv * (n >> 2) + blockIdx.x;     // quartile interleave
  const float W0 = W[0], W1 = W[1], W2 = W[2];
  const float bb = bias[0];

  const float4 me = sx[t];                          // enumerate via x-sorted
  const float xi = me.x, yi = me.y, zi = me.z;
  const int orig = __float_as_int(me.w);

  // ---- choose axis with max |coord| (wave-uniform) ----
  const float ax = fabsf(xi), ay = fabsf(yi), az = fabsf(zi);
  const float4* sv; const int* cur; float cq;
  if (ay >= ax && ay >= az)      { sv = sy; cur = cy; cq = yi; }
  else if (az >= ax && az >= ay) { sv = sz; cur = cz; cq = zi; }
  else                           { sv = sx; cur = cx; cq = xi; }

  // ---- bin-estimated rank -> seed window ----
  const int bq = bin_of(cq);
  const int bs = (bq > 0) ? cur[bq - 1] : 0;
  const int be = cur[bq];
  int lo = ((bs + be) >> 1) - SEED / 2;
  lo = lo < 0 ? 0 : lo;
  lo = lo > n - SEED ? n - SEED : lo;
  const float4* base = sv + lo + lane;

  // ---- 1. seed lane-minima ----
  float m = BIG;
#pragma unroll
  for (int s = 0; s < SEED / 64; ++s) {
    const float4 c = base[s * 64];
    const float dx = xi - c.x, dy = yi - c.y, dz = zi - c.z;
    m = fminf(m, fmaf(dx, dx, fmaf(dy, dy, dz * dz)));
  }

  // ---- 2. u = 12th smallest of the 64 lane minima ----
  float u;
  {
    float v = m;
#pragma unroll
    for (int r = 0; r < KK; ++r) {
      const float mm = wave_min(v);
      u = mm;
      v = (v == mm) ? BIG : v;
    }
  }

  // ---- 3. extent from prefix sums: {|c - cq| <= sqrt(u)} ⊆ [lo2, hi2) ----
  const float s = sqrtf(u);
  const int bl = bin_of(cq - s);
  const int bh = bin_of(cq + s);
  const int lo2 = (bl > 0) ? cur[bl - 1] : 0;
  const int hi2 = cur[bh];
  const int steps = (hi2 - lo2 + 63) >> 6;

  // ---- collect-scan: fixed-trip, break-free ----
  float qd[CD], qw[CD];
  int ccnt = 0;
#pragma unroll
  for (int k = 0; k < CD; ++k) { qd[k] = BIG; qw[k] = 0.f; }

  int st = 0;
  for (; st + 2 <= steps; st += 2) {
    const int p0 = lo2 + st * 64 + lane;
    const int p1 = p0 + 64;
    const float4 c0 = sv[p0];
    const float4 c1 = sv[(p1 < hi2) ? p1 : hi2 - 1];
    {
      const float dx = xi - c0.x, dy = yi - c0.y, dz = zi - c0.z;
      const float d2 = fmaf(dx, dx, fmaf(dy, dy, dz * dz));
      if (d2 <= u) {
        const float w = fmaf(W0, fabsf(dx), fmaf(W1, fabsf(dy), W2 * fabsf(dz)));
        ++ccnt; ins4(qd, qw, d2, w);
      }
    }
    if (p1 < hi2) {
      const float dx = xi - c1.x, dy = yi - c1.y, dz = zi - c1.z;
      const float d2 = fmaf(dx, dx, fmaf(dy, dy, dz * dz));
      if (d2 <= u) {
        const float w = fmaf(W0, fabsf(dx), fmaf(W1, fabsf(dy), W2 * fabsf(dz)));
        ++ccnt; ins4(qd, qw, d2, w);
      }
    }
  }
  for (; st < steps; ++st) {
    const int pos = lo2 + st * 64 + lane;
    if (pos < hi2) {
      const float4 c = sv[pos];
      const float dx = xi - c.x, dy = yi - c.y, dz = zi - c.z;
      const float d2 = fmaf(dx, dx, fmaf(dy, dy, dz * dz));
      if (d2 <= u) {
        const float w = fmaf(W0, fabsf(dx), fmaf(W1, fabsf(dy), W2 * fabsf(dz)));
        ++ccnt; ins4(qd, qw, d2, w);
      }
    }
  }

  // ---- 4. extract exact 12 smallest ----
  float acc = 0.f;
  const bool ovf = __ballot(ccnt > CD) != 0ULL;   // wave-uniform
  if (!ovf) {
#pragma unroll
    for (int r = 0; r < KK; ++r) {
      const float mm = wave_min(qd[0]);
      const unsigned long long bal = __ballot(qd[0] == mm);
      if (qd[0] == mm && lane == (int)(__ffsll(bal) - 1)) {
        acc += qw[0];
#pragma unroll
        for (int k = 0; k < CD - 1; ++k) { qd[k] = qd[k + 1]; qw[k] = qw[k + 1]; }
        qd[CD - 1] = BIG;
      }
    }
  } else {
    // rare exact fallback over the same extent: med3 top-12 -> tau -> rescan
    float dd[KK];
#pragma unroll
    for (int k = 0; k < KK; ++k) dd[k] = BIG;
    for (int s0 = 0; s0 < steps; ++s0) {
      const int pos = lo2 + s0 * 64 + lane;
      const float4 c = sv[(pos < hi2) ? pos : hi2 - 1];
      const float dx = xi - c.x, dy = yi - c.y, dz = zi - c.z;
      const float d2 = (pos < hi2) ? fmaf(dx, dx, fmaf(dy, dy, dz * dz)) : BIG;
#pragma unroll
      for (int k = KK - 1; k >= 1; --k)
        dd[k] = __builtin_amdgcn_fmed3f(d2, dd[k - 1], dd[k]);
      dd[0] = fminf(dd[0], d2);
    }
    float tau = 0.f;
#pragma unroll
    for (int r = 0; r < KK; ++r) {
      const float mm = wave_min(dd[0]);
      if (dd[0] == mm) {
#pragma unroll
        for (int k = 0; k < KK - 1; ++k) dd[k] = dd[k + 1];
        dd[KK - 1] = BIG;
      }
      tau = mm;
    }
    for (int s0 = 0; s0 < steps; ++s0) {
      const int pos = lo2 + s0 * 64 + lane;
      if (pos < hi2) {
        const float4 c = sv[pos];
        const float dx = xi - c.x, dy = yi - c.y, dz = zi - c.z;
        const float d2 = fmaf(dx, dx, fmaf(dy, dy, dz * dz));
        const float w  = fmaf(W0, fabsf(dx), fmaf(W1, fabsf(dy), W2 * fabsf(dz)));
        acc += (d2 <= tau) ? w : 0.f;
      }
    }
  }

  // ---- 5. reduce + write ----
#pragma unroll
  for (int o = 1; o < 64; o <<= 1) acc += __shfl_xor(acc, o);
  if (lane == 0) {
    const float xw0 = W0 * xi + W1 * yi + W2 * zi;
    // 1 + 11/sqrt(2)
    out[orig] = bb + (xw0 * 8.778174593052022f + 0.5f * acc) * (1.0f / 12.0f);
  }
}

extern "C" void kernel_launch(void* const* d_in, const int* in_sizes, int n_in,
                              void* d_out, int out_size, void* d_ws, size_t ws_size,
                              hipStream_t stream) {
  const float* p  = (const float*)d_in[0];
  const float* W  = (const float*)d_in[1];
  const float* bb = (const float*)d_in[2];
  float* out = (float*)d_out;

  const int n = in_sizes[0] / 3;   // 16384

  // ws: hist 3x2048 @0 | cursorEnd 3x2048 @24576 | scatCur 3x2048 @49152
  //     | sorted 3xn float4 @73728
  int*    hist      = (int*)d_ws;
  int*    cursorEnd = (int*)((char*)d_ws + 24576);
  int*    scatCur   = (int*)((char*)d_ws + 49152);
  float4* s_all     = (float4*)((char*)d_ws + 73728);

  int*    cx = cursorEnd;
  int*    cy = cx + NBINS;
  int*    cz = cy + NBINS;
  float4* sx = s_all;
  float4* sy = sx + n;
  float4* sz = sy + n;

  const int wide = (n + 255) / 256;   // 64 blocks

  hipMemsetAsync(hist, 0, 3 * NBINS * 4, stream);
  hist_kernel<<<wide, 256, 0, stream>>>(p, hist, n);
  scan_kernel<<<3, 1024, 0, stream>>>(hist, cursorEnd, scatCur);
  scatter_kernel<<<wide, 256, 0, stream>>>(p, scatCur, s_all, n);
  query_kernel<<<n / WPB, BLOCK, 0, stream>>>(sx, sy, sz, cx, cy, cz, W, bb, out, n);
}